// Round 13
// baseline (247.093 us; speedup 1.0000x reference)
//
#include <hip/hip_runtime.h>
#include <hip/hip_bf16.h>
#include <math.h>

#define D_MODEL 512
#define N_HEADS 8
#define HEAD_DIM 64
#define BATCH 2
#define SEQ 4096
#define M_ROWS (BATCH*SEQ)   // 8192

typedef __attribute__((ext_vector_type(8))) short short8;
typedef __attribute__((ext_vector_type(4))) float f32x4;
typedef __attribute__((ext_vector_type(16))) float f32x16;
typedef __attribute__((ext_vector_type(2))) unsigned uint2v;

__device__ inline short f2bf(float f) {
  union { float f; unsigned u; } v; v.f = f;
  unsigned u = v.u;
  unsigned r = u + 0x7FFFu + ((u >> 16) & 1u);
  return (short)(r >> 16);
}

__device__ inline unsigned cvtpk_bf16(float lo, float hi) {
  unsigned r;
  asm("v_cvt_pk_bf16_f32 %0, %1, %2" : "=v"(r) : "v"(lo), "v"(hi));
  return r;
}

__device__ inline void gll16(const void* g, void* l) {
  __builtin_amdgcn_global_load_lds(
      (const __attribute__((address_space(1))) unsigned int*)g,
      (__attribute__((address_space(3))) unsigned int*)l, 16, 0, 0);
}

__device__ inline short8 cvt8(float4 a, float4 b) {
  short8 o;
  o[0] = f2bf(a.x); o[1] = f2bf(a.y); o[2] = f2bf(a.z); o[3] = f2bf(a.w);
  o[4] = f2bf(b.x); o[5] = f2bf(b.y); o[6] = f2bf(b.z); o[7] = f2bf(b.w);
  return o;
}

__device__ inline short8 mk8(unsigned a, unsigned b, unsigned c, unsigned d) {
  union { unsigned u[4]; short8 s; } x;
  x.u[0] = a; x.u[1] = b; x.u[2] = c; x.u[3] = d;
  return x.s;
}

// ---------------- prep: vectorized casts + rope tables ----------------
#define XOCT (M_ROWS*D_MODEL/8)      // 524288
#define WOCT (3*D_MODEL*D_MODEL/8)   // 98304
#define OOCT (D_MODEL*D_MODEL/8)     // 32768
__global__ void prep_kernel(const float* __restrict__ x,
                            const float* __restrict__ Wq,
                            const float* __restrict__ Wk,
                            const float* __restrict__ Wv,
                            const float* __restrict__ Wo,
                            short* __restrict__ xb,
                            short* __restrict__ Wqkv,
                            short* __restrict__ Wob,
                            float* __restrict__ cosT,
                            float* __restrict__ sinT) {
  int i = blockIdx.x * blockDim.x + threadIdx.x;
  if (i < XOCT) {
    float4 a = *(const float4*)&x[i * 8];
    float4 b = *(const float4*)&x[i * 8 + 4];
    *(short8*)&xb[i * 8] = cvt8(a, b);
  }
  if (i < WOCT) {
    int e = i * 8;
    int t = e >> 18, r = e & 262143;
    const float* W = (t == 0) ? Wq : ((t == 1) ? Wk : Wv);
    float4 a = *(const float4*)&W[r];
    float4 b = *(const float4*)&W[r + 4];
    *(short8*)&Wqkv[e] = cvt8(a, b);
  }
  if (i < OOCT) {
    float4 a = *(const float4*)&Wo[i * 8];
    float4 b = *(const float4*)&Wo[i * 8 + 4];
    *(short8*)&Wob[i * 8] = cvt8(a, b);
  }
  if (i < SEQ * 32) {
    int s = i >> 5, p = i & 31;
    float e = (float)(2 * p) * (1.0f / 64.0f);
    float inv = powf(10000.0f, -e);
    float ang = (float)s * inv;
    float sv, cv;
    sincosf(ang, &sv, &cv);
    cosT[i] = cv; sinT[i] = sv;
  }
}

// ---------------- GEMM (unchanged from round 11, passed absmax 0.0156) --------
template<int MODE>
__global__ __launch_bounds__(256) void gemm_kernel(const short* __restrict__ A,
                                                   const short* __restrict__ B,
                                                   float* __restrict__ out_f,
                                                   short* __restrict__ Qb,
                                                   short* __restrict__ Kb,
                                                   short* __restrict__ Vb,
                                                   const float* __restrict__ cosT,
                                                   const float* __restrict__ sinT) {
  __shared__ short smem[18432];                  // 36864 B
  short (*Cs)[136] = (short(*)[136])smem;        // epilogue reuse

  const int m0 = blockIdx.x * 128;
  const int n0 = blockIdx.y * 128;
  const int tid = threadIdx.x;
  const int lane = tid & 63, wid = tid >> 6;
  const int wm = wid >> 1, wn = wid & 1;
  const int l15 = lane & 15, g = lane >> 4;

  const int srow8 = lane >> 3;
  const int sblk = (lane & 7) ^ srow8;

  f32x4 acc[4][4] = {};

  for (int kt = 0; kt < 512; kt += 64) {
    __syncthreads();
#pragma unroll
    for (int cc = 0; cc < 4; ++cc) {
      int row = (cc * 4 + wid) * 8 + srow8;
      gll16(&A[(m0 + row) * 512 + kt + sblk * 8], smem + (cc * 4 + wid) * 512);
      gll16(&B[(n0 + row) * 512 + kt + sblk * 8], smem + 8192 + (cc * 4 + wid) * 512);
    }
    __syncthreads();
#pragma unroll
    for (int kk = 0; kk < 64; kk += 32) {
      short8 a[4], b[4];
#pragma unroll
      for (int mi = 0; mi < 4; ++mi) {
        int row = wm * 64 + mi * 16 + l15;
        a[mi] = *(const short8*)&smem[row * 64 + ((((kk >> 3) + g) ^ (l15 & 7)) << 3)];
      }
#pragma unroll
      for (int ni = 0; ni < 4; ++ni) {
        int row = wn * 64 + ni * 16 + l15;
        b[ni] = *(const short8*)&smem[8192 + row * 64 + ((((kk >> 3) + g) ^ (l15 & 7)) << 3)];
      }
#pragma unroll
      for (int mi = 0; mi < 4; ++mi)
#pragma unroll
        for (int ni = 0; ni < 4; ++ni)
          acc[mi][ni] = __builtin_amdgcn_mfma_f32_16x16x32_bf16(a[mi], b[ni], acc[mi][ni], 0, 0, 0);
    }
  }

  if (MODE == 1) {
    for (int mi = 0; mi < 4; ++mi)
      for (int ni = 0; ni < 4; ++ni)
        for (int r = 0; r < 4; ++r) {
          int row_g = m0 + wm * 64 + mi * 16 + (g << 2) + r;
          int col_g = n0 + wn * 64 + ni * 16 + l15;
          out_f[row_g * 512 + col_g] = acc[mi][ni][r];
        }
    return;
  }

  const int t_blk = n0 >> 9;
  __syncthreads();

  if (t_blk < 2) {
    const float qs = (t_blk == 0) ? 0.18033688011112042f : 1.0f;  // 0.125*log2e
    for (int mi = 0; mi < 4; ++mi)
      for (int ni = 0; ni < 4; ++ni)
        for (int r = 0; r < 4; ++r) {
          int lrow = wm * 64 + mi * 16 + (g << 2) + r;
          int ss = (m0 + lrow) & 4095;
          int d = (n0 + wn * 64 + ni * 16 + l15) & 63;
          int p = d >> 1;
          float c = cosT[ss * 32 + p], s = sinT[ss * 32 + p];
          float v = acc[mi][ni][r];
          float partner = __shfl_xor(v, 1);
          float res = (l15 & 1) ? (v * c + partner * s) : (v * c - partner * s);
          Cs[lrow][wn * 64 + ni * 16 + l15] = f2bf(res * qs);
        }
  } else {
    for (int mi = 0; mi < 4; ++mi)
      for (int ni = 0; ni < 4; ++ni)
        for (int r = 0; r < 4; ++r)
          Cs[wm * 64 + mi * 16 + (g << 2) + r][wn * 64 + ni * 16 + l15] =
              f2bf(acc[mi][ni][r]);
  }
  __syncthreads();

  if (t_blk < 2) {
    short* dst = (t_blk == 0) ? Qb : Kb;
#pragma unroll
    for (int it = 0; it < 8; ++it) {
      int row = (tid >> 4) + (it << 4);
      int colb = (tid & 15) << 3;
      short8 vv = *(const short8*)&Cs[row][colb];
      int row_g = m0 + row;
      int ss = row_g & 4095, bb = row_g >> 12;
      int cc = (n0 + colb) & 511;
      int h = cc >> 6, d = cc & 63;
      *(short8*)&dst[(((bb << 3) + h) * SEQ + ss) * 64 + d] = vv;
    }
  } else {
#pragma unroll
    for (int it = 0; it < 8; ++it) {
      int c = tid & 127;
      int sb = ((tid >> 7) << 3) + (it << 4);
      short8 o8;
#pragma unroll
      for (int j = 0; j < 8; ++j) o8[j] = Cs[sb + j][c];
      int row_g0 = m0 + sb;
      int ss = row_g0 & 4095, bb = row_g0 >> 12;
      int cc = (n0 + c) & 511;
      int h = cc >> 6, d = cc & 63;
      *(short8*)&Vb[((long)(((bb << 3) + h) * 64 + d)) * SEQ + ss] = o8;
    }
  }
}

// ---------------- flash attention: 32x32x16 MFMA, in-reg P via permlane ------
// Identical to round 12 EXCEPT the permlane32_swap exchange, now via the
// builtin with corrected operand order:
//   {W_lo, W_hi} = permlane32_swap(pw[4k+i], pw[4k+2+i])
//   W_lo = {lanes<32: own pw[4k+i]; lanes>=32: partner pw[4k+2+i]}  (word i)
//   W_hi = {lanes<32: partner pw[4k+i]; lanes>=32: own pw[4k+2+i]}  (word 2+i)
__global__ __launch_bounds__(512, 2) void attn_kernel(const short* __restrict__ Q,
                                                      const short* __restrict__ K,
                                                      const short* __restrict__ Vt,
                                                      short* __restrict__ O) {
  __shared__ short Ks[2][64 * 64];
  __shared__ short Vs[2][64 * 64];

  const int o = blockIdx.x;            // 0..255
  const int bh = o & 15;
  const int pr = o >> 4;               // 0..15
  const int tid = threadIdx.x, lane = tid & 63, w = tid >> 6;
  const int l31 = lane & 31, hl = lane >> 5;
  const long base = (long)bh * SEQ * 64;
  const long baseV = (long)bh * 64 * SEQ;
  const int bb = bh >> 3, h = bh & 7;

  const int srow = tid >> 3;
  const int sc16k = (tid & 7) ^ (srow & 7);
  short* segK0 = &Ks[0][(tid >> 6) << 9];
  short* segK1 = &Ks[1][(tid >> 6) << 9];
  short* segV0 = &Vs[0][(tid >> 6) << 9];
  short* segV1 = &Vs[1][(tid >> 6) << 9];

#pragma unroll
  for (int ti = 0; ti < 2; ++ti) {
    const int tile = ti ? (15 - pr) : pr;
    const int q0w = (tile << 8) + (w << 5);
    const int nc = (tile + 1) << 2;

    short8 qf[4];
#pragma unroll
    for (int kb = 0; kb < 4; ++kb)
      qf[kb] = *(const short8*)&Q[base + (long)(q0w + l31) * 64 + kb * 16 + hl * 8];

    f32x16 oa0 = {}, oa1 = {};
    float m_r = -__builtin_inff(), l_r = 0.f;

    __syncthreads();   // prev pass's reads of buffers done
    gll16(&K[base + (long)srow * 64 + sc16k * 8], segK0);
    gll16(&Vt[baseV + (long)srow * SEQ + sc16k * 8], segV0);

    for (int c = 0; c < nc; ++c) {
      const int kv0 = c << 6;
      const int bi = c & 1;
      __syncthreads();   // stage(c) complete + prev reads of other buffer done
      if (c + 1 < nc) {
        const int nkv = (c + 1) << 6;
        short* dK = (bi ? segK0 : segK1);
        short* dV = (bi ? segV0 : segV1);
        gll16(&K[base + (long)(nkv + srow) * 64 + sc16k * 8], dK);
        gll16(&Vt[baseV + (long)srow * SEQ + nkv + sc16k * 8], dV);
      }
      if (kv0 > q0w + 31) continue;    // wave fully masked (uniform per wave)

      // ---- S^T = K Q^T : C col = q (l31), rows = kv ----
      f32x16 s0 = {}, s1 = {};
      __builtin_amdgcn_s_setprio(1);
#pragma unroll
      for (int kb = 0; kb < 4; ++kb) {
        int blk = 2 * kb + hl;
        short8 a0 = *(const short8*)&Ks[bi][l31 * 64 + ((blk ^ (l31 & 7)) << 3)];
        short8 a1 = *(const short8*)&Ks[bi][(32 + l31) * 64 + ((blk ^ (l31 & 7)) << 3)];
        s0 = __builtin_amdgcn_mfma_f32_32x32x16_bf16(a0, qf[kb], s0, 0, 0, 0);
        s1 = __builtin_amdgcn_mfma_f32_32x32x16_bf16(a1, qf[kb], s1, 0, 0, 0);
      }
      __builtin_amdgcn_s_setprio(0);

      if (kv0 + 63 > q0w) {            // boundary: causal mask
        int q = q0w + l31;
#pragma unroll
        for (int r = 0; r < 16; ++r) {
          int kvr = kv0 + (r & 3) + ((r >> 2) << 3) + (hl << 2);
          if (kvr > q) s0[r] = -__builtin_inff();
          if (kvr + 32 > q) s1[r] = -__builtin_inff();
        }
      }

      // ---- defer-max softmax (scalar per-lane state, pair-synced) ----
      float pmx = s0[0];
#pragma unroll
      for (int r = 1; r < 16; ++r) pmx = fmaxf(pmx, s0[r]);
#pragma unroll
      for (int r = 0; r < 16; ++r) pmx = fmaxf(pmx, s1[r]);
      if (!__all(pmx <= m_r + 8.f)) {  // rare (always at c==0)
        float pm = fmaxf(pmx, __shfl_xor(pmx, 32));
        float mn = fmaxf(m_r, pm);
        float alpha = exp2f(m_r - mn);
        m_r = mn;
        l_r *= alpha;
#pragma unroll
        for (int r = 0; r < 16; ++r) {
          int qq = (r & 3) + ((r >> 2) << 3) + (hl << 2);
          float ar = __shfl(alpha, qq);
          oa0[r] *= ar; oa1[r] *= ar;
        }
      }
      float sum = 0.f;
#pragma unroll
      for (int r = 0; r < 16; ++r) { s0[r] = exp2f(s0[r] - m_r); sum += s0[r]; }
#pragma unroll
      for (int r = 0; r < 16; ++r) { s1[r] = exp2f(s1[r] - m_r); sum += s1[r]; }
      l_r += sum;

      // ---- pack P -> bf16 words; permlane32_swap builds A-frags ----
      unsigned pw[16];
#pragma unroll
      for (int i = 0; i < 8; ++i) pw[i]     = cvtpk_bf16(s0[2 * i], s0[2 * i + 1]);
#pragma unroll
      for (int i = 0; i < 8; ++i) pw[8 + i] = cvtpk_bf16(s1[2 * i], s1[2 * i + 1]);
#pragma unroll
      for (int gq = 0; gq < 4; ++gq) {
        uint2v e0 = __builtin_amdgcn_permlane32_swap(pw[gq * 4 + 0], pw[gq * 4 + 2], false, false);
        uint2v e1 = __builtin_amdgcn_permlane32_swap(pw[gq * 4 + 1], pw[gq * 4 + 3], false, false);
        pw[gq * 4 + 0] = e0.x; pw[gq * 4 + 2] = e0.y;
        pw[gq * 4 + 1] = e1.x; pw[gq * 4 + 3] = e1.y;
      }

      // ---- PV: o += P[q][kv] V[kv][d] ----
      __builtin_amdgcn_s_setprio(1);
#pragma unroll
      for (int kb2 = 0; kb2 < 4; ++kb2) {
        short8 pa = mk8(pw[kb2 * 4], pw[kb2 * 4 + 1], pw[kb2 * 4 + 2], pw[kb2 * 4 + 3]);
        int blk = 2 * kb2 + hl;
        short8 bv0 = *(const short8*)&Vs[bi][l31 * 64 + ((blk ^ (l31 & 7)) << 3)];
        short8 bv1 = *(const short8*)&Vs[bi][(32 + l31) * 64 + ((blk ^ (l31 & 7)) << 3)];
        oa0 = __builtin_amdgcn_mfma_f32_32x32x16_bf16(pa, bv0, oa0, 0, 0, 0);
        oa1 = __builtin_amdgcn_mfma_f32_32x32x16_bf16(pa, bv1, oa1, 0, 0, 0);
      }
      __builtin_amdgcn_s_setprio(0);
    }

    // ---- epilogue: combine pair l, write O ----
    float lf = l_r + __shfl_xor(l_r, 32);
#pragma unroll
    for (int r = 0; r < 16; ++r) {
      int qq = (r & 3) + ((r >> 2) << 3) + (hl << 2);
      float lq = __shfl(lf, qq);
      int q = q0w + qq;
      long rowb = ((long)(bb * SEQ + q)) * 512 + h * 64;
      O[rowb + l31]      = f2bf(oa0[r] / lq);
      O[rowb + 32 + l31] = f2bf(oa1[r] / lq);
    }
  }
}

extern "C" void kernel_launch(void* const* d_in, const int* in_sizes, int n_in,
                              void* d_out, int out_size, void* d_ws, size_t ws_size,
                              hipStream_t stream) {
  const float* x  = (const float*)d_in[0];
  const float* Wq = (const float*)d_in[1];
  const float* Wk = (const float*)d_in[2];
  const float* Wv = (const float*)d_in[3];
  const float* Wo = (const float*)d_in[4];

  char* ws = (char*)d_ws;
  size_t off = 0;
  auto alloc = [&](size_t bytes) {
    void* p = ws + off;
    off += (bytes + 255) & ~(size_t)255;
    return p;
  };
  short* xb   = (short*)alloc((size_t)M_ROWS * 512 * 2);
  short* Wqkv = (short*)alloc((size_t)1536 * 512 * 2);
  short* Wob  = (short*)alloc((size_t)512 * 512 * 2);
  float* cosT = (float*)alloc((size_t)SEQ * 32 * 4);
  float* sinT = (float*)alloc((size_t)SEQ * 32 * 4);
  short* Qb   = (short*)alloc((size_t)16 * SEQ * 64 * 2);
  short* Kb   = (short*)alloc((size_t)16 * SEQ * 64 * 2);
  short* Vt   = (short*)alloc((size_t)16 * SEQ * 64 * 2);
  short* Obuf = (short*)alloc((size_t)M_ROWS * 512 * 2);

  prep_kernel<<<2048, 256, 0, stream>>>(x, Wq, Wk, Wv, Wo, xb, Wqkv, Wob, cosT, sinT);
  gemm_kernel<0><<<dim3(64, 12), 256, 0, stream>>>(xb, Wqkv, nullptr, Qb, Kb, Vt, cosT, sinT);
  attn_kernel<<<256, 512, 0, stream>>>(Qb, Kb, Vt, Obuf);
  gemm_kernel<1><<<dim3(64, 4), 256, 0, stream>>>(Obuf, Wob, (float*)d_out, nullptr, nullptr, nullptr, nullptr, nullptr);
}